// Round 1
// baseline (203.177 us; speedup 1.0000x reference)
//
#include <hip/hip_runtime.h>
#include <hip/hip_bf16.h>

typedef __hip_bfloat16 bf16;
typedef __attribute__((ext_vector_type(8))) short bf16x8;
typedef __attribute__((ext_vector_type(4))) float floatx4;

#define NB 16
#define NC 256
#define NPIX 4096
#define NHID 128
#define NH 4
#define ND 32
#define NMEM 4
#define QSCALE 0.17677669529663687f  // 32^-0.5

__device__ __forceinline__ void dma16(const void* g, void* l){
  __builtin_amdgcn_global_load_lds(
      (const __attribute__((address_space(1))) unsigned int*)g,
      (__attribute__((address_space(3))) unsigned int*)l, 16, 0, 0);
}

// ---------------- K0: zero atomic accumulators
__global__ void k0_zero(float* __restrict__ p, int n){
  int i = blockIdx.x*256 + threadIdx.x;
  if (i < n) p[i] = 0.f;
}

// ---------------- kW: pack wqkv*g -> bf16 in MFMA A-frag tile order.
// 16B chunk u: slice s=u/1536, tile=(u%1536)>>6, lane l=u&63;
// row = tile*16 + (l&15); k = s*32 + (l>>4)*8 + j (j=0..7).
__launch_bounds__(256)
__global__ void kW(const float* __restrict__ wqkv, const float* __restrict__ g,
                   bf16* __restrict__ wgpack){
  const int u = blockIdx.x*256 + threadIdx.x;     // 12288 chunks
  const int s = u / 1536;
  const int r = u - s*1536;
  const int tile = r >> 6, l = r & 63;
  const int row = tile*16 + (l & 15);
  const int kb  = s*32 + (l >> 4)*8;
  const float* wp = wqkv + (size_t)row*NC + kb;
  floatx4 w0 = *(const floatx4*)wp;
  floatx4 w1 = *(const floatx4*)(wp + 4);
  floatx4 g0 = *(const floatx4*)(g + kb);
  floatx4 g1 = *(const floatx4*)(g + kb + 4);
  alignas(16) bf16 tmp[8];
  #pragma unroll
  for (int i = 0; i < 4; ++i){
    tmp[i]   = __float2bfloat16(w0[i]*g0[i]);
    tmp[4+i] = __float2bfloat16(w1[i]*g1[i]);
  }
  *(uint4*)(wgpack + (size_t)u*8) = *(const uint4*)tmp;
}

// ---------------- kA v2: fused norm + qkv GEMM + q-softmax + P/ctx/z.
// 512 threads / 8 waves: wave = (row-group rg = wv&3 -> 96 rows, px-half ph = wv>>2 -> 32 px).
// x^T staged ONCE (33.8KB LDS); weight DMA single-buffered but overlapped with MFMA:
//   read frags -> barrier -> DMA(s+1) -> MFMA(s) -> barrier.
// acc[6][2] = 48 AGPR; __launch_bounds__(512,4) caps regs at 128 -> 2 blocks/CU.
__launch_bounds__(512, 4)
__global__ void kA(const float* __restrict__ x, const bf16* __restrict__ wgpack,
                   float* __restrict__ dout,
                   float* __restrict__ ctxu, float* __restrict__ zacc){
  __shared__ char smem alignas(16) [60672];
  bf16* Ab = (bf16*)smem;                        // 24 tiles x 1KB = 24576 (GEMM)
  bf16 (*Xb)[264] = (bf16(*)[264])(smem + 24576);// [64][264] = 33792, ends 58368 (GEMM)
  bf16 (*Pb)[72] = (bf16(*)[72])smem;            // [128][72] = 18432 (post, alias)
  bf16 (*Vb)[72] = (bf16(*)[72])(smem + 18432);  // [128][72] = 18432 (post, alias)
  float* ssqL = (float*)(smem + 58368);          // [8][64] = 2048
  float* sL   = (float*)(smem + 60416);          // [64]
  float* cxL  = (float*)smem;                    // [4][32][32] f32 = 16KB (post-ctx, alias)
  const int t = threadIdx.x;
  const int pb = blockIdx.x * 64, b = blockIdx.y;
  const int wv = t >> 6, lane = t & 63, m = lane & 15, q4 = lane >> 4;
  const int rg = wv & 3, ph = wv >> 2;
  const float* xb = x + (size_t)b*NC*NPIX;

  {  // prologue DMA: Ab step 0 (wave wv: tiles wv*3..+3)
    const bf16* gt = wgpack + ((size_t)(wv*3)*64 + lane)*8;
    char* lt = smem + wv*3072;
    #pragma unroll
    for (int tt = 0; tt < 3; ++tt) dma16(gt + tt*512, lt + tt*1024);
  }
  {  // stage ALL of x^T (bf16) + ssq partials: thread t -> px=lane, chans wv*8 + s4*64 + j
    float ssq = 0.f;
    #pragma unroll
    for (int s4 = 0; s4 < 4; ++s4){
      const float* xp = xb + (size_t)(s4*64 + wv*8)*NPIX + pb + lane;
      alignas(16) bf16 tmp[8];
      #pragma unroll
      for (int j = 0; j < 8; ++j){
        float v = xp[(size_t)j*NPIX];
        ssq += v*v;
        tmp[j] = __float2bfloat16(v);
      }
      *(uint4*)&Xb[lane][s4*64 + wv*8] = *(const uint4*)tmp;
    }
    ssqL[wv*64 + lane] = ssq;
  }
  __syncthreads();   // Xb + ssqL visible; prologue DMA drained
  if (t < 64){
    float tot = 0.f;
    #pragma unroll
    for (int i = 0; i < 8; ++i) tot += ssqL[i*64 + t];
    sL[t] = 16.0f / fmaxf(sqrtf(tot), 1e-12f);
  }
  floatx4 acc[6][2] = {};
  for (int s = 0; s < 8; ++s){
    bf16x8 bfr[2], af[6];
    #pragma unroll
    for (int pt = 0; pt < 2; ++pt)
      bfr[pt] = *(const bf16x8*)&Xb[(ph*2 + pt)*16 + m][s*32 + q4*8];
    #pragma unroll
    for (int rt = 0; rt < 6; ++rt)
      af[rt] = *(const bf16x8*)(Ab + (size_t)(rg*6 + rt)*512 + (q4*16 + m)*8);
    __syncthreads();   // all waves done reading Ab[s] (lgkm drained at barrier)
    if (s < 7){        // DMA next weight K-slice; flight hides under MFMA
      const bf16* gt = wgpack + ((size_t)((s+1)*24 + wv*3)*64 + lane)*8;
      char* lt = smem + wv*3072;
      #pragma unroll
      for (int tt = 0; tt < 3; ++tt) dma16(gt + tt*512, lt + tt*1024);
    }
    #pragma unroll
    for (int rt = 0; rt < 6; ++rt)
      #pragma unroll
      for (int pt = 0; pt < 2; ++pt)
        acc[rt][pt] = __builtin_amdgcn_mfma_f32_16x16x32_bf16(af[rt], bfr[pt], acc[rt][pt], 0, 0, 0);
    __syncthreads();   // DMA(s+1) visible
  }
  // ---- post phase: rows rg*96..+96, px ph*32..+32 (gpt = ph*2+pt)
  float sv[2];
  #pragma unroll
  for (int pt = 0; pt < 2; ++pt) sv[pt] = sL[(ph*2 + pt)*16 + m];
  #pragma unroll
  for (int pr = 0; pr < 3; ++pr){
    const int ra = 2*pr, rb = 2*pr + 1;
    const int row0 = rg*96 + pr*32;
    const int type = row0 >> 7;          // 0=q, 1=k, 2=v
    if (type == 0){
      const int slice = row0 >> 5;       // head = q k-slice
      const int j0 = (q4 & 1)*4;
      #pragma unroll
      for (int pt = 0; pt < 2; ++pt){
        const int gpt = ph*2 + pt;
        float va[4], vb4[4];
        float mx = -1e30f;
        #pragma unroll
        for (int r = 0; r < 4; ++r){
          va[r]  = acc[ra][pt][r]*sv[pt];
          vb4[r] = acc[rb][pt][r]*sv[pt];
          mx = fmaxf(mx, fmaxf(va[r], vb4[r]));
        }
        mx = fmaxf(mx, __shfl_xor(mx, 16, 64));
        mx = fmaxf(mx, __shfl_xor(mx, 32, 64));
        float se = 0.f;
        #pragma unroll
        for (int r = 0; r < 4; ++r){
          va[r] = __expf(va[r] - mx); vb4[r] = __expf(vb4[r] - mx);
          se += va[r] + vb4[r];
        }
        se += __shfl_xor(se, 16, 64);
        se += __shfl_xor(se, 32, 64);
        const float inv = QSCALE / se;
        alignas(8) bf16 pka[4], pkb[4];
        #pragma unroll
        for (int r = 0; r < 4; ++r){
          pka[r] = __float2bfloat16(va[r]*inv);
          pkb[r] = __float2bfloat16(vb4[r]*inv);
        }
        const int ca = (slice*4 + gpt)*4 + (q4 >> 1);
        const int cb = ca + 2;
        bf16* pa = (bf16*)(dout + (size_t)(b*NC + ca)*NPIX + pb) + m*8 + j0;
        bf16* pv = (bf16*)(dout + (size_t)(b*NC + cb)*NPIX + pb) + m*8 + j0;
        *(uint2*)pa = *(const uint2*)pka;
        *(uint2*)pv = *(const uint2*)pkb;
      }
    } else if (type == 1){
      const int d0 = row0 - 128;
      float za[4] = {}, zb[4] = {};
      #pragma unroll
      for (int pt = 0; pt < 2; ++pt){
        const int gpt = ph*2 + pt;
        #pragma unroll
        for (int r = 0; r < 4; ++r){
          float pa = __expf(acc[ra][pt][r]*sv[pt]);
          float pv = __expf(acc[rb][pt][r]*sv[pt]);
          za[r] += pa; zb[r] += pv;
          Pb[d0      + q4*4 + r][gpt*16 + m] = __float2bfloat16(pa);
          Pb[d0 + 16 + q4*4 + r][gpt*16 + m] = __float2bfloat16(pv);
        }
      }
      #pragma unroll
      for (int r = 0; r < 4; ++r){
        #pragma unroll
        for (int o = 1; o < 16; o <<= 1){
          za[r] += __shfl_xor(za[r], o, 64);
          zb[r] += __shfl_xor(zb[r], o, 64);
        }
      }
      if (m == 0){
        #pragma unroll
        for (int r = 0; r < 4; ++r){
          atomicAdd(&zacc[b*NHID + d0      + q4*4 + r], za[r]);
          atomicAdd(&zacc[b*NHID + d0 + 16 + q4*4 + r], zb[r]);
        }
      }
    } else {
      const int v0 = row0 - 256;
      #pragma unroll
      for (int pt = 0; pt < 2; ++pt){
        const int gpt = ph*2 + pt;
        #pragma unroll
        for (int r = 0; r < 4; ++r){
          Vb[v0      + q4*4 + r][gpt*16 + m] = __float2bfloat16(acc[ra][pt][r]*sv[pt]);
          Vb[v0 + 16 + q4*4 + r][gpt*16 + m] = __float2bfloat16(acc[rb][pt][r]*sv[pt]);
        }
      }
    }
  }
  __syncthreads();
  // ctx MFMA: wave = (head rg, token-half ph); each does one 32-tok K-step
  floatx4 cx[2][2] = {};
  {
    const int k0t = ph*32;
    bf16x8 paf[2], pvf[2];
    #pragma unroll
    for (int dt = 0; dt < 2; ++dt) paf[dt] = *(const bf16x8*)&Pb[rg*32 + dt*16 + m][k0t + q4*8];
    #pragma unroll
    for (int et = 0; et < 2; ++et) pvf[et] = *(const bf16x8*)&Vb[rg*32 + et*16 + m][k0t + q4*8];
    #pragma unroll
    for (int dt = 0; dt < 2; ++dt)
      #pragma unroll
      for (int et = 0; et < 2; ++et)
        cx[dt][et] = __builtin_amdgcn_mfma_f32_16x16x32_bf16(paf[dt], pvf[et], cx[dt][et], 0, 0, 0);
  }
  __syncthreads();   // Pb/Vb reads complete -> cxL (alias) writable
  if (ph == 1){      // token-half 1 parks its partial in LDS (halves global atomics)
    #pragma unroll
    for (int dt = 0; dt < 2; ++dt)
      #pragma unroll
      for (int et = 0; et < 2; ++et)
        #pragma unroll
        for (int r = 0; r < 4; ++r)
          cxL[rg*1024 + (dt*16 + q4*4 + r)*32 + et*16 + m] = cx[dt][et][r];
  }
  __syncthreads();
  if (ph == 0){
    float* cb2 = ctxu + (size_t)(b*NH + rg)*ND*ND;
    #pragma unroll
    for (int dt = 0; dt < 2; ++dt)
      #pragma unroll
      for (int et = 0; et < 2; ++et)
        #pragma unroll
        for (int r = 0; r < 4; ++r)
          atomicAdd(&cb2[(dt*16 + q4*4 + r)*ND + et*16 + m],
                    cx[dt][et][r] + cxL[rg*1024 + (dt*16 + q4*4 + r)*32 + et*16 + m]);
  }
}

// ---------------- K4: Weff -> bf16, packed in MFMA A-frag tile order for k5.
// element (b,o,hd): slice=hd>>5, tile=o>>4, q4k=(hd>>3)&3, m=o&15, j=hd&7
__launch_bounds__(256)
__global__ void k4_weff(const float* __restrict__ ctxu, const float* __restrict__ zacc,
                        const float* __restrict__ memkv, const float* __restrict__ wout,
                        bf16* __restrict__ wpack){
  const int idx = blockIdx.x*256 + threadIdx.x;   // (b*256 + o)*128 + hd
  const int b   = idx >> 15;
  const int o   = (idx >> 7) & 255;
  const int hd  = idx & 127;
  const int h = hd >> 5, d = hd & 31;
  const float* mk = memkv + hd*NMEM;                       // mem_kv[0][h][d][j]
  float me[4];
  float z = zacc[b*NHID + hd];
  #pragma unroll
  for (int j = 0; j < 4; ++j){ me[j] = __expf(mk[j]); z += me[j]; }
  const float invz = 1.0f / z;
  const float* cp = ctxu + (size_t)((b*NH + h)*ND + d)*ND;
  const float* wp = wout + (size_t)o*NHID + h*ND;
  const float* mv = memkv + (size_t)(NHID + h*ND)*NMEM;    // mem_kv[1][h][e][j]
  float acc = 0.f;
  #pragma unroll
  for (int e = 0; e < ND; ++e){
    float ce = cp[e];
    #pragma unroll
    for (int j = 0; j < 4; ++j) ce += me[j]*mv[e*NMEM + j];
    acc += ce*wp[e];
  }
  const int slice = hd >> 5, q4k = (hd >> 3) & 3, j = hd & 7;
  const int tile = o >> 4, m16 = o & 15;
  wpack[((size_t)((b*4 + slice)*16 + tile)*64 + q4k*16 + m16)*8 + j] = __float2bfloat16(acc*invz);
}

// ---------------- K5 v2: MFMA y = Weff @ q_s + bias -> RMSNorm -> dout rows 0..255.
// All 16 Q-tiles DMA'd once in prologue; Wb single-buffered with
// read-frags/barrier/DMA-next/MFMA overlap. 4 blocks/CU target.
__launch_bounds__(256, 4)
__global__ void k5_out(float* dout, const bf16* __restrict__ wpack,
                       const float* __restrict__ bout, const float* __restrict__ gout){
  __shared__ char smem alignas(16) [34048];
  bf16* Wb = (bf16*)smem;                 // 16 tiles x 1KB = 16384 (current step)
  bf16* Qb = (bf16*)(smem + 16384);       // 16 tiles x 1KB = 16384 (all steps)
  float* red = (float*)(smem + 32768);    // [4][64]
  float* nf  = (float*)(smem + 33792);    // [64]
  const int t = threadIdx.x;
  const int pb = blockIdx.x * 64, b = blockIdx.y;
  const int wv = t >> 6, lane = t & 63, m = lane & 15, q4 = lane >> 4;
  {  // DMA all Qb: wave wv tiles wv*4..+4; tile tau <- dout row tau*4+q4, bytes pb*4+m*16
    #pragma unroll
    for (int i = 0; i < 4; ++i){
      const int tau = wv*4 + i;
      const char* gq = (const char*)(dout + (size_t)(b*NC + tau*4 + q4)*NPIX + pb) + m*16;
      dma16(gq, smem + 16384 + tau*1024);
    }
  }
  {  // DMA Wb step 0
    const bf16* gt = wpack + ((size_t)((b*4)*16 + wv*4)*64 + lane)*8;
    char* lt = smem + wv*4096;
    #pragma unroll
    for (int tt = 0; tt < 4; ++tt) dma16(gt + tt*512, lt + tt*1024);
  }
  __syncthreads();
  floatx4 acc[4][4] = {};
  for (int s = 0; s < 4; ++s){
    bf16x8 bfr[4], af[4];
    #pragma unroll
    for (int pt = 0; pt < 4; ++pt)
      bfr[pt] = *(const bf16x8*)(Qb + (size_t)(s*4 + pt)*512 + (q4*16 + m)*8);
    #pragma unroll
    for (int rt = 0; rt < 4; ++rt)
      af[rt] = *(const bf16x8*)(Wb + (size_t)(wv*4 + rt)*512 + (q4*16 + m)*8);
    __syncthreads();   // all waves done reading Wb[s]
    if (s < 3){
      const bf16* gt = wpack + ((size_t)((b*4 + s+1)*16 + wv*4)*64 + lane)*8;
      char* lt = smem + wv*4096;
      #pragma unroll
      for (int tt = 0; tt < 4; ++tt) dma16(gt + tt*512, lt + tt*1024);
    }
    #pragma unroll
    for (int rt = 0; rt < 4; ++rt)
      #pragma unroll
      for (int pt = 0; pt < 4; ++pt)
        acc[rt][pt] = __builtin_amdgcn_mfma_f32_16x16x32_bf16(af[rt], bfr[pt], acc[rt][pt], 0, 0, 0);
    __syncthreads();   // DMA(s+1) visible
  }
  // bias + ssq partials
  float ps[4] = {0.f, 0.f, 0.f, 0.f};
  #pragma unroll
  for (int rt = 0; rt < 4; ++rt){
    const int row = wv*64 + rt*16 + q4*4;
    #pragma unroll
    for (int r = 0; r < 4; ++r){
      const float bias = bout[row + r];
      #pragma unroll
      for (int pt = 0; pt < 4; ++pt){
        acc[rt][pt][r] += bias;
        ps[pt] += acc[rt][pt][r]*acc[rt][pt][r];
      }
    }
  }
  #pragma unroll
  for (int pt = 0; pt < 4; ++pt){
    ps[pt] += __shfl_xor(ps[pt], 16, 64);
    ps[pt] += __shfl_xor(ps[pt], 32, 64);
  }
  __syncthreads();
  if (q4 == 0){
    #pragma unroll
    for (int pt = 0; pt < 4; ++pt) red[wv*64 + pt*16 + m] = ps[pt];
  }
  __syncthreads();
  if (t < 64){
    float tot = red[t] + red[64 + t] + red[128 + t] + red[192 + t];
    nf[t] = 16.0f / fmaxf(sqrtf(tot), 1e-12f);
  }
  __syncthreads();
  float nv[4];
  #pragma unroll
  for (int pt = 0; pt < 4; ++pt) nv[pt] = nf[pt*16 + m];
  #pragma unroll
  for (int rt = 0; rt < 4; ++rt){
    const int row = wv*64 + rt*16 + q4*4;
    #pragma unroll
    for (int r = 0; r < 4; ++r){
      const float gg = gout[row + r];
      float* op = dout + (size_t)(b*NC + row + r)*NPIX + pb + m;
      #pragma unroll
      for (int pt = 0; pt < 4; ++pt)
        op[pt*16] = acc[rt][pt][r]*nv[pt]*gg;
    }
  }
}

extern "C" void kernel_launch(void* const* d_in, const int* in_sizes, int n_in,
                              void* d_out, int out_size, void* d_ws, size_t ws_size,
                              hipStream_t stream) {
  (void)in_sizes; (void)n_in; (void)out_size; (void)ws_size;
  const float* x     = (const float*)d_in[0];
  const float* ng    = (const float*)d_in[1];
  const float* wqkv  = (const float*)d_in[2];
  const float* memkv = (const float*)d_in[3];
  const float* wout  = (const float*)d_in[4];
  const float* bout  = (const float*)d_in[5];
  const float* gout  = (const float*)d_in[6];
  float* dout = (float*)d_out;
  char* ws = (char*)d_ws;
  // workspace layout — total 1,515,520 B (~1.45 MB)
  bf16*  wgpack = (bf16*)(ws);              // 8*24*64*8*2  = 196608
  bf16*  wpack  = (bf16*)(ws + 196608);     // 16*4*16*64*8*2 = 1048576
  float* ctxu   = (float*)(ws + 1245184);   // 16*4*32*32*4 = 262144
  float* zacc   = (float*)(ws + 1507328);   // 16*128*4     = 8192

  k0_zero<<<dim3(264),     256, 0, stream>>>(ctxu, 65536 + 2048);
  kW     <<<dim3(48),      256, 0, stream>>>(wqkv, ng, wgpack);
  kA     <<<dim3(64, 16),  512, 0, stream>>>(x, wgpack, dout, ctxu, zacc);
  k4_weff<<<dim3(2048),    256, 0, stream>>>(ctxu, zacc, memkv, wout, wpack);
  k5_out <<<dim3(64, 16),  256, 0, stream>>>(dout, wpack, bout, gout);
}

// Round 2
// 188.272 us; speedup vs baseline: 1.0792x; 1.0792x over previous
//
#include <hip/hip_runtime.h>
#include <hip/hip_bf16.h>

typedef __hip_bfloat16 bf16;
typedef __attribute__((ext_vector_type(8))) short bf16x8;
typedef __attribute__((ext_vector_type(4))) float floatx4;

#define NB 16
#define NC 256
#define NPIX 4096
#define NHID 128
#define NH 4
#define ND 32
#define NMEM 4
#define QSCALE 0.17677669529663687f  // 32^-0.5

__device__ __forceinline__ void dma16(const void* g, void* l){
  __builtin_amdgcn_global_load_lds(
      (const __attribute__((address_space(1))) unsigned int*)g,
      (__attribute__((address_space(3))) unsigned int*)l, 16, 0, 0);
}

// ---------------- K0: zero atomic accumulators
__global__ void k0_zero(float* __restrict__ p, int n){
  int i = blockIdx.x*256 + threadIdx.x;
  if (i < n) p[i] = 0.f;
}

// ---------------- kW: pack wqkv*g -> bf16 in MFMA A-frag tile order.
__launch_bounds__(256)
__global__ void kW(const float* __restrict__ wqkv, const float* __restrict__ g,
                   bf16* __restrict__ wgpack){
  const int u = blockIdx.x*256 + threadIdx.x;     // 12288 chunks
  const int s = u / 1536;
  const int r = u - s*1536;
  const int tile = r >> 6, l = r & 63;
  const int row = tile*16 + (l & 15);
  const int kb  = s*32 + (l >> 4)*8;
  const float* wp = wqkv + (size_t)row*NC + kb;
  floatx4 w0 = *(const floatx4*)wp;
  floatx4 w1 = *(const floatx4*)(wp + 4);
  floatx4 g0 = *(const floatx4*)(g + kb);
  floatx4 g1 = *(const floatx4*)(g + kb + 4);
  alignas(16) bf16 tmp[8];
  #pragma unroll
  for (int i = 0; i < 4; ++i){
    tmp[i]   = __float2bfloat16(w0[i]*g0[i]);
    tmp[4+i] = __float2bfloat16(w1[i]*g1[i]);
  }
  *(uint4*)(wgpack + (size_t)u*8) = *(const uint4*)tmp;
}

// ---------------- kA v3: v1 structure (256 thr / 4 waves / acc[6][4]) +
// double-buffered Ab/Xb with T3-minimum pipeline: stage(s+1) BEFORE compute(s),
// ONE barrier per K-step (v1 had two + drain right after issue).
__launch_bounds__(256)
__global__ void kA(const float* __restrict__ x, const bf16* __restrict__ wgpack,
                   float* __restrict__ dout,
                   float* __restrict__ ctxu, float* __restrict__ zacc){
  __shared__ char smem alignas(16) [60672];
  // GEMM phase: Ab[buf] @ buf*24576 (24 tiles x 1KB); Xb[buf][64][40]bf16 @ 49152+buf*5120
  bf16 (*Pb)[72] = (bf16(*)[72])smem;            // [128][72] = 18432 (post, alias)
  bf16 (*Vb)[72] = (bf16(*)[72])(smem + 18432);  // [128][72] = 18432 (post, alias)
  float* ssqL = (float*)(smem + 59392);          // [4][64]
  float* sL   = (float*)(smem + 60416);          // [64]
  const int t = threadIdx.x;
  const int pb = blockIdx.x * 64, b = blockIdx.y;
  const int wv = t >> 6, lane = t & 63, m = lane & 15, q4 = lane >> 4;
  const int px_st = t & 63, cg_st = t >> 6;
  const float* xb = x + (size_t)b*NC*NPIX;
  float ssq = 0.f;

  auto stage = [&](int s, int buf){
    // DMA w: wave wv loads its own 6 tiles into Ab[buf]
    const bf16* gt = wgpack + ((size_t)(s*24 + wv*6)*64 + lane)*8;
    char* lt = smem + buf*24576 + wv*6144;
    #pragma unroll
    for (int tt = 0; tt < 6; ++tt)
      dma16(gt + tt*512, lt + tt*1024);
    // stage x^T chunk + ssq partials into Xb[buf]
    const float* xp = xb + (size_t)(s*32 + cg_st*8)*NPIX + pb + px_st;
    alignas(16) bf16 tmp[8];
    #pragma unroll
    for (int j = 0; j < 8; ++j){
      float v = xp[(size_t)j*NPIX];
      ssq += v*v;
      tmp[j] = __float2bfloat16(v);
    }
    bf16 (*Xb)[40] = (bf16(*)[40])(smem + 49152 + buf*5120);
    *(uint4*)&Xb[px_st][cg_st*8] = *(const uint4*)tmp;
  };

  stage(0, 0);
  __syncthreads();   // drain prologue DMA + ds_writes
  floatx4 acc[6][4] = {};
  for (int s = 0; s < 8; ++s){
    const int buf = s & 1;
    if (s < 7) stage(s + 1, buf ^ 1);   // flight hides under reads+MFMA of step s
    bf16 (*Xb)[40] = (bf16(*)[40])(smem + 49152 + buf*5120);
    const bf16* Ab = (const bf16*)(smem + buf*24576);
    bf16x8 bfr[4];
    #pragma unroll
    for (int pt = 0; pt < 4; ++pt)
      bfr[pt] = *(const bf16x8*)&Xb[pt*16 + m][q4*8];
    #pragma unroll
    for (int rt = 0; rt < 6; ++rt){
      bf16x8 af = *(const bf16x8*)(Ab + (size_t)wv*3072 + rt*512 + (q4*16 + m)*8);
      #pragma unroll
      for (int pt = 0; pt < 4; ++pt)
        acc[rt][pt] = __builtin_amdgcn_mfma_f32_16x16x32_bf16(af, bfr[pt], acc[rt][pt], 0, 0, 0);
    }
    __syncthreads();   // one barrier/step: drains DMA(s+1), x ds_writes, frag reads
  }
  // finalize s (per px)
  ssqL[cg_st*64 + px_st] = ssq;
  __syncthreads();
  if (t < 64){
    float tot = ssqL[t] + ssqL[64 + t] + ssqL[128 + t] + ssqL[192 + t];
    sL[t] = 16.0f / fmaxf(sqrtf(tot), 1e-12f);
  }
  __syncthreads();   // sL ready; GEMM reads done -> Pb/Vb (alias Ab) writable
  float sv[4];
  #pragma unroll
  for (int pt = 0; pt < 4; ++pt) sv[pt] = sL[pt*16 + m];
  #pragma unroll
  for (int pr = 0; pr < 3; ++pr){
    const int ra = 2*pr, rb = 2*pr + 1;
    const int row0 = wv*96 + pr*32;
    const int type = row0 >> 7;          // 0=q, 1=k, 2=v
    if (type == 0){
      const int slice = row0 >> 5;       // head = q k-slice
      const int j0 = (q4 & 1)*4;
      #pragma unroll
      for (int pt = 0; pt < 4; ++pt){
        float va[4], vb[4];
        float mx = -1e30f;
        #pragma unroll
        for (int r = 0; r < 4; ++r){
          va[r] = acc[ra][pt][r]*sv[pt];
          vb[r] = acc[rb][pt][r]*sv[pt];
          mx = fmaxf(mx, fmaxf(va[r], vb[r]));
        }
        mx = fmaxf(mx, __shfl_xor(mx, 16, 64));
        mx = fmaxf(mx, __shfl_xor(mx, 32, 64));
        float se = 0.f;
        #pragma unroll
        for (int r = 0; r < 4; ++r){
          va[r] = __expf(va[r] - mx); vb[r] = __expf(vb[r] - mx);
          se += va[r] + vb[r];
        }
        se += __shfl_xor(se, 16, 64);
        se += __shfl_xor(se, 32, 64);
        const float inv = QSCALE / se;
        alignas(8) bf16 pka[4], pkb[4];
        #pragma unroll
        for (int r = 0; r < 4; ++r){
          pka[r] = __float2bfloat16(va[r]*inv);
          pkb[r] = __float2bfloat16(vb[r]*inv);
        }
        const int ca = (slice*4 + pt)*4 + (q4 >> 1);
        const int cb = ca + 2;
        bf16* pa = (bf16*)(dout + (size_t)(b*NC + ca)*NPIX + pb) + m*8 + j0;
        bf16* pv = (bf16*)(dout + (size_t)(b*NC + cb)*NPIX + pb) + m*8 + j0;
        *(uint2*)pa = *(const uint2*)pka;
        *(uint2*)pv = *(const uint2*)pkb;
      }
    } else if (type == 1){
      const int d0 = row0 - 128;
      float za[4] = {}, zb[4] = {};
      #pragma unroll
      for (int pt = 0; pt < 4; ++pt){
        #pragma unroll
        for (int r = 0; r < 4; ++r){
          float pa = __expf(acc[ra][pt][r]*sv[pt]);
          float pv = __expf(acc[rb][pt][r]*sv[pt]);
          za[r] += pa; zb[r] += pv;
          Pb[d0      + q4*4 + r][pt*16 + m] = __float2bfloat16(pa);
          Pb[d0 + 16 + q4*4 + r][pt*16 + m] = __float2bfloat16(pv);
        }
      }
      #pragma unroll
      for (int r = 0; r < 4; ++r){
        #pragma unroll
        for (int o = 1; o < 16; o <<= 1){
          za[r] += __shfl_xor(za[r], o, 64);
          zb[r] += __shfl_xor(zb[r], o, 64);
        }
      }
      if (m == 0){
        #pragma unroll
        for (int r = 0; r < 4; ++r){
          atomicAdd(&zacc[b*NHID + d0      + q4*4 + r], za[r]);
          atomicAdd(&zacc[b*NHID + d0 + 16 + q4*4 + r], zb[r]);
        }
      }
    } else {
      const int v0 = row0 - 256;
      #pragma unroll
      for (int pt = 0; pt < 4; ++pt)
        #pragma unroll
        for (int r = 0; r < 4; ++r){
          Vb[v0      + q4*4 + r][pt*16 + m] = __float2bfloat16(acc[ra][pt][r]*sv[pt]);
          Vb[v0 + 16 + q4*4 + r][pt*16 + m] = __float2bfloat16(acc[rb][pt][r]*sv[pt]);
        }
    }
  }
  __syncthreads();
  // ctx MFMA: wave wv = head wv; 64 toks in 2 K-steps
  floatx4 cx[2][2] = {};
  #pragma unroll
  for (int k0t = 0; k0t < 64; k0t += 32){
    bf16x8 af[2], bf[2];
    #pragma unroll
    for (int dt = 0; dt < 2; ++dt) af[dt] = *(const bf16x8*)&Pb[wv*32 + dt*16 + m][k0t + q4*8];
    #pragma unroll
    for (int et = 0; et < 2; ++et) bf[et] = *(const bf16x8*)&Vb[wv*32 + et*16 + m][k0t + q4*8];
    #pragma unroll
    for (int dt = 0; dt < 2; ++dt)
      #pragma unroll
      for (int et = 0; et < 2; ++et)
        cx[dt][et] = __builtin_amdgcn_mfma_f32_16x16x32_bf16(af[dt], bf[et], cx[dt][et], 0, 0, 0);
  }
  float* cb2 = ctxu + (size_t)(b*NH + wv)*ND*ND;
  #pragma unroll
  for (int dt = 0; dt < 2; ++dt)
    #pragma unroll
    for (int et = 0; et < 2; ++et)
      #pragma unroll
      for (int r = 0; r < 4; ++r)
        atomicAdd(&cb2[(dt*16 + q4*4 + r)*ND + et*16 + m], cx[dt][et][r]);
}

// ---------------- K4: Weff -> bf16, packed in MFMA A-frag tile order for k5.
__launch_bounds__(256)
__global__ void k4_weff(const float* __restrict__ ctxu, const float* __restrict__ zacc,
                        const float* __restrict__ memkv, const float* __restrict__ wout,
                        bf16* __restrict__ wpack){
  const int idx = blockIdx.x*256 + threadIdx.x;   // (b*256 + o)*128 + hd
  const int b   = idx >> 15;
  const int o   = (idx >> 7) & 255;
  const int hd  = idx & 127;
  const int h = hd >> 5, d = hd & 31;
  const float* mk = memkv + hd*NMEM;                       // mem_kv[0][h][d][j]
  float me[4];
  float z = zacc[b*NHID + hd];
  #pragma unroll
  for (int j = 0; j < 4; ++j){ me[j] = __expf(mk[j]); z += me[j]; }
  const float invz = 1.0f / z;
  const float* cp = ctxu + (size_t)((b*NH + h)*ND + d)*ND;
  const float* wp = wout + (size_t)o*NHID + h*ND;
  const float* mv = memkv + (size_t)(NHID + h*ND)*NMEM;    // mem_kv[1][h][e][j]
  float acc = 0.f;
  #pragma unroll
  for (int e = 0; e < ND; ++e){
    float ce = cp[e];
    #pragma unroll
    for (int j = 0; j < 4; ++j) ce += me[j]*mv[e*NMEM + j];
    acc += ce*wp[e];
  }
  const int slice = hd >> 5, q4k = (hd >> 3) & 3, j = hd & 7;
  const int tile = o >> 4, m16 = o & 15;
  wpack[((size_t)((b*4 + slice)*16 + tile)*64 + q4k*16 + m16)*8 + j] = __float2bfloat16(acc*invz);
}

// ---------------- K5 v3: Qb all-prologue; Wb double-buffered, 1 barrier/step.
__launch_bounds__(256)
__global__ void k5_out(float* dout, const bf16* __restrict__ wpack,
                       const float* __restrict__ bout, const float* __restrict__ gout){
  __shared__ char smem alignas(16) [50432];
  // Wb[buf] @ buf*16384 (16 tiles); Qb @32768 (16 tiles); red @49152; nf @50176
  bf16* Qb = (bf16*)(smem + 32768);
  float* red = (float*)(smem + 49152);    // [4][64]
  float* nf  = (float*)(smem + 50176);    // [64]
  const int t = threadIdx.x;
  const int pb = blockIdx.x * 64, b = blockIdx.y;
  const int wv = t >> 6, lane = t & 63, m = lane & 15, q4 = lane >> 4;
  {  // DMA all Qb: wave wv tiles wv*4..+4; tile tau <- dout row tau*4+q4, bytes pb*4+m*16
    #pragma unroll
    for (int i = 0; i < 4; ++i){
      const int tau = wv*4 + i;
      const char* gq = (const char*)(dout + (size_t)(b*NC + tau*4 + q4)*NPIX + pb) + m*16;
      dma16(gq, smem + 32768 + tau*1024);
    }
  }
  {  // DMA Wb step 0 -> buf0
    const bf16* gt = wpack + ((size_t)((b*4)*16 + wv*4)*64 + lane)*8;
    char* lt = smem + wv*4096;
    #pragma unroll
    for (int tt = 0; tt < 4; ++tt) dma16(gt + tt*512, lt + tt*1024);
  }
  __syncthreads();
  floatx4 acc[4][4] = {};
  for (int s = 0; s < 4; ++s){
    const int buf = s & 1;
    if (s < 3){   // DMA next W into other buffer; flight hides under reads+MFMA
      const bf16* gt = wpack + ((size_t)((b*4 + s+1)*16 + wv*4)*64 + lane)*8;
      char* lt = smem + (buf^1)*16384 + wv*4096;
      #pragma unroll
      for (int tt = 0; tt < 4; ++tt) dma16(gt + tt*512, lt + tt*1024);
    }
    const bf16* Wb = (const bf16*)(smem + buf*16384);
    bf16x8 bfr[4], af[4];
    #pragma unroll
    for (int pt = 0; pt < 4; ++pt)
      bfr[pt] = *(const bf16x8*)(Qb + (size_t)(s*4 + pt)*512 + (q4*16 + m)*8);
    #pragma unroll
    for (int rt = 0; rt < 4; ++rt)
      af[rt] = *(const bf16x8*)(Wb + (size_t)(wv*4 + rt)*512 + (q4*16 + m)*8);
    #pragma unroll
    for (int rt = 0; rt < 4; ++rt)
      #pragma unroll
      for (int pt = 0; pt < 4; ++pt)
        acc[rt][pt] = __builtin_amdgcn_mfma_f32_16x16x32_bf16(af[rt], bfr[pt], acc[rt][pt], 0, 0, 0);
    __syncthreads();   // one barrier/step: drains DMA(s+1) + frag reads
  }
  // bias + ssq partials
  float ps[4] = {0.f, 0.f, 0.f, 0.f};
  #pragma unroll
  for (int rt = 0; rt < 4; ++rt){
    const int row = wv*64 + rt*16 + q4*4;
    #pragma unroll
    for (int r = 0; r < 4; ++r){
      const float bias = bout[row + r];
      #pragma unroll
      for (int pt = 0; pt < 4; ++pt){
        acc[rt][pt][r] += bias;
        ps[pt] += acc[rt][pt][r]*acc[rt][pt][r];
      }
    }
  }
  #pragma unroll
  for (int pt = 0; pt < 4; ++pt){
    ps[pt] += __shfl_xor(ps[pt], 16, 64);
    ps[pt] += __shfl_xor(ps[pt], 32, 64);
  }
  if (q4 == 0){
    #pragma unroll
    for (int pt = 0; pt < 4; ++pt) red[wv*64 + pt*16 + m] = ps[pt];
  }
  __syncthreads();
  if (t < 64){
    float tot = red[t] + red[64 + t] + red[128 + t] + red[192 + t];
    nf[t] = 16.0f / fmaxf(sqrtf(tot), 1e-12f);
  }
  __syncthreads();
  float nv[4];
  #pragma unroll
  for (int pt = 0; pt < 4; ++pt) nv[pt] = nf[pt*16 + m];
  #pragma unroll
  for (int rt = 0; rt < 4; ++rt){
    const int row = wv*64 + rt*16 + q4*4;
    #pragma unroll
    for (int r = 0; r < 4; ++r){
      const float gg = gout[row + r];
      float* op = dout + (size_t)(b*NC + row + r)*NPIX + pb + m;
      #pragma unroll
      for (int pt = 0; pt < 4; ++pt)
        op[pt*16] = acc[rt][pt][r]*nv[pt]*gg;
    }
  }
}

extern "C" void kernel_launch(void* const* d_in, const int* in_sizes, int n_in,
                              void* d_out, int out_size, void* d_ws, size_t ws_size,
                              hipStream_t stream) {
  (void)in_sizes; (void)n_in; (void)out_size; (void)ws_size;
  const float* x     = (const float*)d_in[0];
  const float* ng    = (const float*)d_in[1];
  const float* wqkv  = (const float*)d_in[2];
  const float* memkv = (const float*)d_in[3];
  const float* wout  = (const float*)d_in[4];
  const float* bout  = (const float*)d_in[5];
  const float* gout  = (const float*)d_in[6];
  float* dout = (float*)d_out;
  char* ws = (char*)d_ws;
  // workspace layout — total 1,515,520 B (~1.45 MB)
  bf16*  wgpack = (bf16*)(ws);              // 8*24*64*8*2  = 196608
  bf16*  wpack  = (bf16*)(ws + 196608);     // 16*4*16*64*8*2 = 1048576
  float* ctxu   = (float*)(ws + 1245184);   // 16*4*32*32*4 = 262144
  float* zacc   = (float*)(ws + 1507328);   // 16*128*4     = 8192

  k0_zero<<<dim3(264),     256, 0, stream>>>(ctxu, 65536 + 2048);
  kW     <<<dim3(48),      256, 0, stream>>>(wqkv, ng, wgpack);
  kA     <<<dim3(64, 16),  256, 0, stream>>>(x, wgpack, dout, ctxu, zacc);
  k4_weff<<<dim3(2048),    256, 0, stream>>>(ctxu, zacc, memkv, wout, wpack);
  k5_out <<<dim3(64, 16),  256, 0, stream>>>(dout, wpack, bout, gout);
}

// Round 3
// 178.590 us; speedup vs baseline: 1.1377x; 1.0542x over previous
//
#include <hip/hip_runtime.h>
#include <hip/hip_bf16.h>

typedef __hip_bfloat16 bf16;
typedef __attribute__((ext_vector_type(8))) short bf16x8;
typedef __attribute__((ext_vector_type(4))) float floatx4;

#define NB 16
#define NC 256
#define NPIX 4096
#define NHID 128
#define NH 4
#define ND 32
#define NMEM 4
#define QSCALE 0.17677669529663687f  // 32^-0.5

#define VMCNT(n) asm volatile("s_waitcnt vmcnt(" #n ")" ::: "memory")
#define LGKM0()  asm volatile("s_waitcnt lgkmcnt(0)" ::: "memory")
#define SCHEDB() __builtin_amdgcn_sched_barrier(0)

__device__ __forceinline__ void dma16(const void* g, void* l){
  __builtin_amdgcn_global_load_lds(
      (const __attribute__((address_space(1))) unsigned int*)g,
      (__attribute__((address_space(3))) unsigned int*)l, 16, 0, 0);
}

// ---------------- kW: pack wqkv*g -> bf16 in MFMA A-frag tile order.
// Also zeroes the ctxu/zacc accumulators (absorbs old k0).
__launch_bounds__(256)
__global__ void kW(const float* __restrict__ wqkv, const float* __restrict__ g,
                   bf16* __restrict__ wgpack, float* __restrict__ zbase){
  const int u = blockIdx.x*256 + threadIdx.x;     // 12288 chunks
  for (int z = u; z < 65536 + 2048; z += 48*256) zbase[z] = 0.f;
  const int s = u / 1536;
  const int r = u - s*1536;
  const int tile = r >> 6, l = r & 63;
  const int row = tile*16 + (l & 15);
  const int kb  = s*32 + (l >> 4)*8;
  const float* wp = wqkv + (size_t)row*NC + kb;
  floatx4 w0 = *(const floatx4*)wp;
  floatx4 w1 = *(const floatx4*)(wp + 4);
  floatx4 g0 = *(const floatx4*)(g + kb);
  floatx4 g1 = *(const floatx4*)(g + kb + 4);
  alignas(16) bf16 tmp[8];
  #pragma unroll
  for (int i = 0; i < 4; ++i){
    tmp[i]   = __float2bfloat16(w0[i]*g0[i]);
    tmp[4+i] = __float2bfloat16(w1[i]*g1[i]);
  }
  *(uint4*)(wgpack + (size_t)u*8) = *(const uint4*)tmp;
}

// ---------------- kA v4: counted-vmcnt pipeline.
// Wave-private Ab (wave DMAs + reads only its own 6 tiles); Xb cross-wave (barrier).
// Depth-2 x prefetch in regs (issue at s for s+2, ds_write late at s for s+1).
// Barrier waits only vmcnt(8): the 6 DMAs issued ONE step earlier are drained,
// the 8 x-loads issued THIS step stay in flight.
__launch_bounds__(256)
__global__ void kA(const float* __restrict__ x, const bf16* __restrict__ wgpack,
                   float* __restrict__ dout,
                   float* __restrict__ ctxu, float* __restrict__ zacc){
  __shared__ char smem alignas(16) [60672];
  // GEMM: Ab[buf] @ buf*24576 (24 tiles x 1KB); Xb[buf][64][40]bf16 @ 49152+buf*5120
  bf16 (*Pb)[72] = (bf16(*)[72])smem;            // [128][72] = 18432 (post, alias)
  bf16 (*Vb)[72] = (bf16(*)[72])(smem + 18432);  // [128][72] = 18432 (post, alias)
  float* ssqL = (float*)(smem + 59392);          // [4][64]
  float* sL   = (float*)(smem + 60416);          // [64]
  const int t = threadIdx.x;
  const int pb = blockIdx.x * 64, b = blockIdx.y;
  const int wv = t >> 6, lane = t & 63, m = lane & 15, q4 = lane >> 4;
  const int px_st = t & 63, cg_st = t >> 6;
  const float* xb = x + (size_t)b*NC*NPIX;
  float ssq = 0.f;
  float xr[2][8];

  auto xissue = [&](int c, float* dst){   // 8 scalar global loads, no use yet
    const float* xp = xb + (size_t)(c*32 + cg_st*8)*NPIX + pb + px_st;
    #pragma unroll
    for (int j = 0; j < 8; ++j) dst[j] = xp[(size_t)j*NPIX];
  };
  auto xwrite = [&](int c, const float* v){  // cvt + ssq + ds_write into Xb[c&1]
    alignas(16) bf16 tmp[8];
    #pragma unroll
    for (int j = 0; j < 8; ++j){
      ssq += v[j]*v[j];
      tmp[j] = __float2bfloat16(v[j]);
    }
    bf16 (*Xb)[40] = (bf16(*)[40])(smem + 49152 + (c&1)*5120);
    *(uint4*)&Xb[px_st][cg_st*8] = *(const uint4*)tmp;
  };
  auto dmaw = [&](int c){                 // wave-private 6 tiles into Ab[c&1]
    const bf16* gt = wgpack + ((size_t)(c*24 + wv*6)*64 + lane)*8;
    char* lt = smem + (c&1)*24576 + wv*6144;
    #pragma unroll
    for (int tt = 0; tt < 6; ++tt) dma16(gt + tt*512, lt + tt*1024);
  };

  // prologue — issue order pinned: x(0), DMA(0), x(1)
  xissue(0, xr[0]);
  SCHEDB();
  dmaw(0);
  SCHEDB();
  xissue(1, xr[1]);
  SCHEDB();
  xwrite(0, xr[0]);          // auto-waits x(0) regs
  LGKM0();
  VMCNT(8);                  // drains DMA(0); x(1) stays in flight
  __builtin_amdgcn_s_barrier();
  SCHEDB();

  floatx4 acc[6][4] = {};
  #pragma unroll
  for (int s = 0; s < 8; ++s){
    const int buf = s & 1;
    // 1. frag reads of step s
    bf16 (*Xb)[40] = (bf16(*)[40])(smem + 49152 + buf*5120);
    const bf16* Ab = (const bf16*)(smem + buf*24576);
    bf16x8 bfr[4], af[6];
    #pragma unroll
    for (int pt = 0; pt < 4; ++pt)
      bfr[pt] = *(const bf16x8*)&Xb[pt*16 + m][q4*8];
    #pragma unroll
    for (int rt = 0; rt < 6; ++rt)
      af[rt] = *(const bf16x8*)(Ab + (size_t)wv*3072 + rt*512 + (q4*16 + m)*8);
    // 2. DMA weights for s+1 (issue FIRST for vmcnt accounting)
    if (s < 7) dmaw(s + 1);
    SCHEDB();
    // 3. x prefetch for s+2 (these ride across the barrier)
    if (s < 6) xissue(s + 2, xr[buf]);
    SCHEDB();
    // 4. MFMA
    #pragma unroll
    for (int rt = 0; rt < 6; ++rt)
      #pragma unroll
      for (int pt = 0; pt < 4; ++pt)
        acc[rt][pt] = __builtin_amdgcn_mfma_f32_16x16x32_bf16(af[rt], bfr[pt], acc[rt][pt], 0, 0, 0);
    // 5. write x chunk s+1 (auto-waits loads issued one step ago)
    if (s < 7) xwrite(s + 1, xr[buf ^ 1]);
    // 6. sync: DMA(s+1) done (issued one step... this step pt.2, 24 MFMAs ago);
    //    x(s+2) 8 loads remain in flight.
    LGKM0();
    if (s < 6) { VMCNT(8); } else { VMCNT(0); }
    __builtin_amdgcn_s_barrier();
    SCHEDB();
  }
  // finalize s (per px)
  ssqL[cg_st*64 + px_st] = ssq;
  __syncthreads();
  if (t < 64){
    float tot = ssqL[t] + ssqL[64 + t] + ssqL[128 + t] + ssqL[192 + t];
    sL[t] = 16.0f / fmaxf(sqrtf(tot), 1e-12f);
  }
  __syncthreads();   // sL ready; GEMM reads done -> Pb/Vb (alias Ab) writable
  float sv[4];
  #pragma unroll
  for (int pt = 0; pt < 4; ++pt) sv[pt] = sL[pt*16 + m];
  #pragma unroll
  for (int pr = 0; pr < 3; ++pr){
    const int ra = 2*pr, rb = 2*pr + 1;
    const int row0 = wv*96 + pr*32;
    const int type = row0 >> 7;          // 0=q, 1=k, 2=v
    if (type == 0){
      const int slice = row0 >> 5;       // head = q k-slice
      const int j0 = (q4 & 1)*4;
      #pragma unroll
      for (int pt = 0; pt < 4; ++pt){
        float va[4], vb[4];
        float mx = -1e30f;
        #pragma unroll
        for (int r = 0; r < 4; ++r){
          va[r] = acc[ra][pt][r]*sv[pt];
          vb[r] = acc[rb][pt][r]*sv[pt];
          mx = fmaxf(mx, fmaxf(va[r], vb[r]));
        }
        mx = fmaxf(mx, __shfl_xor(mx, 16, 64));
        mx = fmaxf(mx, __shfl_xor(mx, 32, 64));
        float se = 0.f;
        #pragma unroll
        for (int r = 0; r < 4; ++r){
          va[r] = __expf(va[r] - mx); vb[r] = __expf(vb[r] - mx);
          se += va[r] + vb[r];
        }
        se += __shfl_xor(se, 16, 64);
        se += __shfl_xor(se, 32, 64);
        const float inv = QSCALE / se;
        alignas(8) bf16 pka[4], pkb[4];
        #pragma unroll
        for (int r = 0; r < 4; ++r){
          pka[r] = __float2bfloat16(va[r]*inv);
          pkb[r] = __float2bfloat16(vb[r]*inv);
        }
        const int ca = (slice*4 + pt)*4 + (q4 >> 1);
        const int cb = ca + 2;
        bf16* pa = (bf16*)(dout + (size_t)(b*NC + ca)*NPIX + pb) + m*8 + j0;
        bf16* pv = (bf16*)(dout + (size_t)(b*NC + cb)*NPIX + pb) + m*8 + j0;
        *(uint2*)pa = *(const uint2*)pka;
        *(uint2*)pv = *(const uint2*)pkb;
      }
    } else if (type == 1){
      const int d0 = row0 - 128;
      float za[4] = {}, zb[4] = {};
      #pragma unroll
      for (int pt = 0; pt < 4; ++pt){
        #pragma unroll
        for (int r = 0; r < 4; ++r){
          float pa = __expf(acc[ra][pt][r]*sv[pt]);
          float pv = __expf(acc[rb][pt][r]*sv[pt]);
          za[r] += pa; zb[r] += pv;
          Pb[d0      + q4*4 + r][pt*16 + m] = __float2bfloat16(pa);
          Pb[d0 + 16 + q4*4 + r][pt*16 + m] = __float2bfloat16(pv);
        }
      }
      #pragma unroll
      for (int r = 0; r < 4; ++r){
        #pragma unroll
        for (int o = 1; o < 16; o <<= 1){
          za[r] += __shfl_xor(za[r], o, 64);
          zb[r] += __shfl_xor(zb[r], o, 64);
        }
      }
      if (m == 0){
        #pragma unroll
        for (int r = 0; r < 4; ++r){
          atomicAdd(&zacc[b*NHID + d0      + q4*4 + r], za[r]);
          atomicAdd(&zacc[b*NHID + d0 + 16 + q4*4 + r], zb[r]);
        }
      }
    } else {
      const int v0 = row0 - 256;
      #pragma unroll
      for (int pt = 0; pt < 4; ++pt)
        #pragma unroll
        for (int r = 0; r < 4; ++r){
          Vb[v0      + q4*4 + r][pt*16 + m] = __float2bfloat16(acc[ra][pt][r]*sv[pt]);
          Vb[v0 + 16 + q4*4 + r][pt*16 + m] = __float2bfloat16(acc[rb][pt][r]*sv[pt]);
        }
    }
  }
  __syncthreads();
  // ctx MFMA: wave wv = head wv; 64 toks in 2 K-steps
  floatx4 cx[2][2] = {};
  #pragma unroll
  for (int k0t = 0; k0t < 64; k0t += 32){
    bf16x8 af2[2], bf2[2];
    #pragma unroll
    for (int dt = 0; dt < 2; ++dt) af2[dt] = *(const bf16x8*)&Pb[wv*32 + dt*16 + m][k0t + q4*8];
    #pragma unroll
    for (int et = 0; et < 2; ++et) bf2[et] = *(const bf16x8*)&Vb[wv*32 + et*16 + m][k0t + q4*8];
    #pragma unroll
    for (int dt = 0; dt < 2; ++dt)
      #pragma unroll
      for (int et = 0; et < 2; ++et)
        cx[dt][et] = __builtin_amdgcn_mfma_f32_16x16x32_bf16(af2[dt], bf2[et], cx[dt][et], 0, 0, 0);
  }
  float* cb2 = ctxu + (size_t)(b*NH + wv)*ND*ND;
  #pragma unroll
  for (int dt = 0; dt < 2; ++dt)
    #pragma unroll
    for (int et = 0; et < 2; ++et)
      #pragma unroll
      for (int r = 0; r < 4; ++r)
        atomicAdd(&cb2[(dt*16 + q4*4 + r)*ND + et*16 + m], cx[dt][et][r]);
}

// ---------------- k4 v2: 64 blocks (bx=o-quarter, by=b), LDS-staged, coalesced.
// ctx''[h][d][e] = (ctx + mem_v term) * invz, computed once; wout slice padded [64][129].
__launch_bounds__(256)
__global__ void k4_weff(const float* __restrict__ ctxu, const float* __restrict__ zacc,
                        const float* __restrict__ memkv, const float* __restrict__ wout,
                        bf16* __restrict__ wpack){
  __shared__ float ctxL[4][32][32];        // 16384 B
  __shared__ float woutL[64][129];         // 33024 B (pad -> conflict-free col reads)
  const int t = threadIdx.x;
  const int o0 = blockIdx.x * 64, b = blockIdx.y;
  {  // stage wout[o0..o0+64][0..128] (contiguous 8192 floats), coalesced
    const float* ws = wout + (size_t)o0*NHID;
    #pragma unroll
    for (int i = 0; i < 32; ++i){
      const int idx = i*256 + t;
      woutL[idx >> 7][idx & 127] = ws[idx];
    }
  }
  if (t < 128){  // hd = t: fold mem-kv and invz into ctx''
    const int h = t >> 5;
    const float* mk = memkv + t*NMEM;
    float me[4]; float z = zacc[b*NHID + t];
    #pragma unroll
    for (int j = 0; j < 4; ++j){ me[j] = __expf(mk[j]); z += me[j]; }
    const float invz = 1.0f / z;
    const float* cp = ctxu + (size_t)(b*NH*ND + t)*ND;     // (b, h, d, :)
    const float* mv = memkv + (size_t)(NHID + h*ND)*NMEM;  // mem_kv[1][h][e][j]
    #pragma unroll
    for (int e = 0; e < ND; ++e){
      float ce = cp[e];
      #pragma unroll
      for (int j = 0; j < 4; ++j) ce += me[j]*mv[e*NMEM + j];
      ctxL[h][t & 31][e] = ce * invz;
    }
  }
  __syncthreads();
  const int ol = t & 63, g = t >> 6;       // o = o0+ol, head g (one head per wave)
  float out[32] = {};
  #pragma unroll
  for (int e = 0; e < 32; ++e){
    const float we = woutL[ol][g*32 + e];  // conflict-free (129 stride)
    #pragma unroll
    for (int d = 0; d < 32; ++d) out[d] += ctxL[g][d][e] * we;  // broadcast
  }
  const int o = o0 + ol, tile = o >> 4, m16 = o & 15;
  #pragma unroll
  for (int q4k = 0; q4k < 4; ++q4k){
    alignas(16) bf16 tmp[8];
    #pragma unroll
    for (int j = 0; j < 8; ++j) tmp[j] = __float2bfloat16(out[q4k*8 + j]);
    *(uint4*)(wpack + ((size_t)((b*4 + g)*16 + tile)*64 + q4k*16 + m16)*8) = *(const uint4*)tmp;
  }
}

// ---------------- K5 v4: Qb prologue once (one barrier); Wb wave-private
// double-buffer -> NO barriers in K-loop, only own-wave vmcnt(0).
__launch_bounds__(256)
__global__ void k5_out(float* dout, const bf16* __restrict__ wpack,
                       const float* __restrict__ bout, const float* __restrict__ gout){
  __shared__ char smem alignas(16) [50432];
  // Wb[buf] @ buf*16384 (16 tiles); Qb @32768 (16 tiles); red @49152; nf @50176
  bf16* Qb = (bf16*)(smem + 32768);
  float* red = (float*)(smem + 49152);    // [4][64]
  float* nf  = (float*)(smem + 50176);    // [64]
  const int t = threadIdx.x;
  const int pb = blockIdx.x * 64, b = blockIdx.y;
  const int wv = t >> 6, lane = t & 63, m = lane & 15, q4 = lane >> 4;
  {  // DMA all Qb: wave wv tiles wv*4..+4
    #pragma unroll
    for (int i = 0; i < 4; ++i){
      const int tau = wv*4 + i;
      const char* gq = (const char*)(dout + (size_t)(b*NC + tau*4 + q4)*NPIX + pb) + m*16;
      dma16(gq, smem + 32768 + tau*1024);
    }
  }
  {  // DMA Wb step 0 -> buf0 (wave-private region)
    const bf16* gt = wpack + ((size_t)((b*4)*16 + wv*4)*64 + lane)*8;
    char* lt = smem + wv*4096;
    #pragma unroll
    for (int tt = 0; tt < 4; ++tt) dma16(gt + tt*512, lt + tt*1024);
  }
  VMCNT(0);
  __builtin_amdgcn_s_barrier();
  SCHEDB();
  floatx4 acc[4][4] = {};
  #pragma unroll
  for (int s = 0; s < 4; ++s){
    const int buf = s & 1;
    const bf16* Wb = (const bf16*)(smem + buf*16384);
    bf16x8 bfr[4], af[4];
    #pragma unroll
    for (int pt = 0; pt < 4; ++pt)
      bfr[pt] = *(const bf16x8*)(Qb + (size_t)(s*4 + pt)*512 + (q4*16 + m)*8);
    #pragma unroll
    for (int rt = 0; rt < 4; ++rt)
      af[rt] = *(const bf16x8*)(Wb + (size_t)(wv*4 + rt)*512 + (q4*16 + m)*8);
    if (s < 3){   // next W into other (own-wave) buffer
      const bf16* gt = wpack + ((size_t)((b*4 + s+1)*16 + wv*4)*64 + lane)*8;
      char* lt = smem + (buf^1)*16384 + wv*4096;
      #pragma unroll
      for (int tt = 0; tt < 4; ++tt) dma16(gt + tt*512, lt + tt*1024);
    }
    SCHEDB();
    #pragma unroll
    for (int rt = 0; rt < 4; ++rt)
      #pragma unroll
      for (int pt = 0; pt < 4; ++pt)
        acc[rt][pt] = __builtin_amdgcn_mfma_f32_16x16x32_bf16(af[rt], bfr[pt], acc[rt][pt], 0, 0, 0);
    if (s < 3) { VMCNT(0); }   // own DMA visible before next iter's ds_reads
    SCHEDB();
  }
  // bias + ssq partials
  float ps[4] = {0.f, 0.f, 0.f, 0.f};
  #pragma unroll
  for (int rt = 0; rt < 4; ++rt){
    const int row = wv*64 + rt*16 + q4*4;
    #pragma unroll
    for (int r = 0; r < 4; ++r){
      const float bias = bout[row + r];
      #pragma unroll
      for (int pt = 0; pt < 4; ++pt){
        acc[rt][pt][r] += bias;
        ps[pt] += acc[rt][pt][r]*acc[rt][pt][r];
      }
    }
  }
  #pragma unroll
  for (int pt = 0; pt < 4; ++pt){
    ps[pt] += __shfl_xor(ps[pt], 16, 64);
    ps[pt] += __shfl_xor(ps[pt], 32, 64);
  }
  if (q4 == 0){
    #pragma unroll
    for (int pt = 0; pt < 4; ++pt) red[wv*64 + pt*16 + m] = ps[pt];
  }
  __syncthreads();
  if (t < 64){
    float tot = red[t] + red[64 + t] + red[128 + t] + red[192 + t];
    nf[t] = 16.0f / fmaxf(sqrtf(tot), 1e-12f);
  }
  __syncthreads();
  float nv[4];
  #pragma unroll
  for (int pt = 0; pt < 4; ++pt) nv[pt] = nf[pt*16 + m];
  #pragma unroll
  for (int rt = 0; rt < 4; ++rt){
    const int row = wv*64 + rt*16 + q4*4;
    #pragma unroll
    for (int r = 0; r < 4; ++r){
      const float gg = gout[row + r];
      float* op = dout + (size_t)(b*NC + row + r)*NPIX + pb + m;
      #pragma unroll
      for (int pt = 0; pt < 4; ++pt)
        op[pt*16] = acc[rt][pt][r]*nv[pt]*gg;
    }
  }
}

extern "C" void kernel_launch(void* const* d_in, const int* in_sizes, int n_in,
                              void* d_out, int out_size, void* d_ws, size_t ws_size,
                              hipStream_t stream) {
  (void)in_sizes; (void)n_in; (void)out_size; (void)ws_size;
  const float* x     = (const float*)d_in[0];
  const float* ng    = (const float*)d_in[1];
  const float* wqkv  = (const float*)d_in[2];
  const float* memkv = (const float*)d_in[3];
  const float* wout  = (const float*)d_in[4];
  const float* bout  = (const float*)d_in[5];
  const float* gout  = (const float*)d_in[6];
  float* dout = (float*)d_out;
  char* ws = (char*)d_ws;
  // workspace layout — total 1,515,520 B (~1.45 MB)
  bf16*  wgpack = (bf16*)(ws);              // 8*24*64*8*2  = 196608
  bf16*  wpack  = (bf16*)(ws + 196608);     // 16*4*16*64*8*2 = 1048576
  float* ctxu   = (float*)(ws + 1245184);   // 16*4*32*32*4 = 262144
  float* zacc   = (float*)(ws + 1507328);   // 16*128*4     = 8192

  kW     <<<dim3(48),      256, 0, stream>>>(wqkv, ng, wgpack, ctxu);  // also zeroes ctxu+zacc
  kA     <<<dim3(64, 16),  256, 0, stream>>>(x, wgpack, dout, ctxu, zacc);
  k4_weff<<<dim3(4, 16),   256, 0, stream>>>(ctxu, zacc, memkv, wout, wpack);
  k5_out <<<dim3(64, 16),  256, 0, stream>>>(dout, wpack, bout, gout);
}

// Round 5
// 176.447 us; speedup vs baseline: 1.1515x; 1.0121x over previous
//
#include <hip/hip_runtime.h>
#include <hip/hip_bf16.h>

typedef __hip_bfloat16 bf16;
typedef __attribute__((ext_vector_type(8))) short bf16x8;
typedef __attribute__((ext_vector_type(4))) float floatx4;

#define NB 16
#define NC 256
#define NPIX 4096
#define NHID 128
#define NH 4
#define ND 32
#define NMEM 4
#define QSCALE 0.17677669529663687f  // 32^-0.5

#define LGKM0()  asm volatile("s_waitcnt lgkmcnt(0)" ::: "memory")

// ---------------- kW: pack wqkv*g -> bf16 in MFMA A-frag tile order.
// Also zeroes the ctxu/zacc accumulators.
__launch_bounds__(256)
__global__ void kW(const float* __restrict__ wqkv, const float* __restrict__ g,
                   bf16* __restrict__ wgpack, float* __restrict__ zbase){
  const int u = blockIdx.x*256 + threadIdx.x;     // 12288 chunks
  for (int z = u; z < 65536 + 2048; z += 48*256) zbase[z] = 0.f;
  const int s = u / 1536;
  const int r = u - s*1536;
  const int tile = r >> 6, l = r & 63;
  const int row = tile*16 + (l & 15);
  const int kb  = s*32 + (l >> 4)*8;
  const float* wp = wqkv + (size_t)row*NC + kb;
  floatx4 w0 = *(const floatx4*)wp;
  floatx4 w1 = *(const floatx4*)(wp + 4);
  floatx4 g0 = *(const floatx4*)(g + kb);
  floatx4 g1 = *(const floatx4*)(g + kb + 4);
  alignas(16) bf16 tmp[8];
  #pragma unroll
  for (int i = 0; i < 4; ++i){
    tmp[i]   = __float2bfloat16(w0[i]*g0[i]);
    tmp[4+i] = __float2bfloat16(w1[i]*g1[i]);
  }
  *(uint4*)(wgpack + (size_t)u*8) = *(const uint4*)tmp;
}

// ---------------- kA v5: weight frags global->REGISTER direct (LDS round trip was a
// lane-identity pass-through). Only Xb (cross-lane x transpose) stays in LDS.
// Loop barrier = lgkmcnt(0)+s_barrier only; weight loads (af) and x loads (xr)
// both ride across barriers as plain register-dest loads.
__launch_bounds__(256)
__global__ void kA(const float* __restrict__ x, const bf16* __restrict__ wgpack,
                   float* __restrict__ dout,
                   float* __restrict__ ctxu, float* __restrict__ zacc){
  __shared__ char smem alignas(16) [48384];
  bf16 (*Pb)[72] = (bf16(*)[72])smem;            // [128][72] = 18432 (post)
  bf16 (*Vb)[72] = (bf16(*)[72])(smem + 18432);  // [128][72] = 18432 (post) -> 36864
  // Xb[buf][64][40] bf16 @ 36864 + buf*5120 (GEMM)
  float* ssqL = (float*)(smem + 47104);          // [4][64]
  float* sL   = (float*)(smem + 48128);          // [64]
  const int t = threadIdx.x;
  const int pb = blockIdx.x * 64, b = blockIdx.y;
  const int wv = t >> 6, lane = t & 63, m = lane & 15, q4 = lane >> 4;
  const int px_st = t & 63, cg_st = t >> 6;
  const float* xb = x + (size_t)b*NC*NPIX;
  float ssq = 0.f;
  float xr[2][8];
  bf16x8 af[2][6];

  auto xissue = [&](int c, float* dst){   // 8 scalar global loads, no use yet
    const float* xp = xb + (size_t)(c*32 + cg_st*8)*NPIX + pb + px_st;
    #pragma unroll
    for (int j = 0; j < 8; ++j) dst[j] = xp[(size_t)j*NPIX];
  };
  auto xwrite = [&](int c, const float* v){  // cvt + ssq + ds_write into Xb[c&1]
    alignas(16) bf16 tmp[8];
    #pragma unroll
    for (int j = 0; j < 8; ++j){
      ssq += v[j]*v[j];
      tmp[j] = __float2bfloat16(v[j]);
    }
    bf16 (*Xb)[40] = (bf16(*)[40])(smem + 36864 + (c&1)*5120);
    *(uint4*)&Xb[px_st][cg_st*8] = *(const uint4*)tmp;
  };
  auto wload = [&](int c, int rt)->bf16x8 {  // wave-private frag, lane-identity
    return *(const bf16x8*)(wgpack + ((size_t)(c*24 + wv*6 + rt)*64 + lane)*8);
  };

  // prologue
  xissue(0, xr[0]);
  #pragma unroll
  for (int rt = 0; rt < 6; ++rt) af[0][rt] = wload(0, rt);
  xissue(1, xr[1]);
  xwrite(0, xr[0]);          // compiler waits the x(0) regs
  LGKM0();
  __builtin_amdgcn_s_barrier();

  floatx4 acc[6][4] = {};
  #pragma unroll
  for (int s = 0; s < 8; ++s){
    const int buf = s & 1;
    bf16 (*Xb)[40] = (bf16(*)[40])(smem + 36864 + buf*5120);
    bf16x8 bfr[4];
    #pragma unroll
    for (int pt = 0; pt < 4; ++pt)
      bfr[pt] = *(const bf16x8*)&Xb[pt*16 + m][q4*8];
    if (s < 7){  // weight frags for s+1: plain loads, ride across the barrier
      #pragma unroll
      for (int rt = 0; rt < 6; ++rt) af[(s+1)&1][rt] = wload(s + 1, rt);
    }
    if (s < 6) xissue(s + 2, xr[buf]);
    #pragma unroll
    for (int rt = 0; rt < 6; ++rt)
      #pragma unroll
      for (int pt = 0; pt < 4; ++pt)
        acc[rt][pt] = __builtin_amdgcn_mfma_f32_16x16x32_bf16(af[buf][rt], bfr[pt], acc[rt][pt], 0, 0, 0);
    if (s < 7) xwrite(s + 1, xr[buf ^ 1]);
    LGKM0();                 // Xb writes visible; no vmcnt wait in the loop
    __builtin_amdgcn_s_barrier();
  }
  // finalize s (per px)
  ssqL[cg_st*64 + px_st] = ssq;
  __syncthreads();
  if (t < 64){
    float tot = ssqL[t] + ssqL[64 + t] + ssqL[128 + t] + ssqL[192 + t];
    sL[t] = 16.0f / fmaxf(sqrtf(tot), 1e-12f);
  }
  __syncthreads();   // sL ready; GEMM Xb reads done -> Pb/Vb writable
  float sv[4];
  #pragma unroll
  for (int pt = 0; pt < 4; ++pt) sv[pt] = sL[pt*16 + m];
  #pragma unroll
  for (int pr = 0; pr < 3; ++pr){
    const int ra = 2*pr, rb = 2*pr + 1;
    const int row0 = wv*96 + pr*32;
    const int type = row0 >> 7;          // 0=q, 1=k, 2=v
    if (type == 0){
      const int slice = row0 >> 5;       // head = q k-slice
      const int j0 = (q4 & 1)*4;
      #pragma unroll
      for (int pt = 0; pt < 4; ++pt){
        float va[4], vb[4];
        float mx = -1e30f;
        #pragma unroll
        for (int r = 0; r < 4; ++r){
          va[r] = acc[ra][pt][r]*sv[pt];
          vb[r] = acc[rb][pt][r]*sv[pt];
          mx = fmaxf(mx, fmaxf(va[r], vb[r]));
        }
        mx = fmaxf(mx, __shfl_xor(mx, 16, 64));
        mx = fmaxf(mx, __shfl_xor(mx, 32, 64));
        float se = 0.f;
        #pragma unroll
        for (int r = 0; r < 4; ++r){
          va[r] = __expf(va[r] - mx); vb[r] = __expf(vb[r] - mx);
          se += va[r] + vb[r];
        }
        se += __shfl_xor(se, 16, 64);
        se += __shfl_xor(se, 32, 64);
        const float inv = QSCALE / se;
        alignas(8) bf16 pka[4], pkb[4];
        #pragma unroll
        for (int r = 0; r < 4; ++r){
          pka[r] = __float2bfloat16(va[r]*inv);
          pkb[r] = __float2bfloat16(vb[r]*inv);
        }
        const int ca = (slice*4 + pt)*4 + (q4 >> 1);
        const int cb = ca + 2;
        bf16* pa = (bf16*)(dout + (size_t)(b*NC + ca)*NPIX + pb) + m*8 + j0;
        bf16* pv = (bf16*)(dout + (size_t)(b*NC + cb)*NPIX + pb) + m*8 + j0;
        *(uint2*)pa = *(const uint2*)pka;
        *(uint2*)pv = *(const uint2*)pkb;
      }
    } else if (type == 1){
      const int d0 = row0 - 128;
      float za[4] = {}, zb[4] = {};
      #pragma unroll
      for (int pt = 0; pt < 4; ++pt){
        #pragma unroll
        for (int r = 0; r < 4; ++r){
          float pa = __expf(acc[ra][pt][r]*sv[pt]);
          float pv = __expf(acc[rb][pt][r]*sv[pt]);
          za[r] += pa; zb[r] += pv;
          Pb[d0      + q4*4 + r][pt*16 + m] = __float2bfloat16(pa);
          Pb[d0 + 16 + q4*4 + r][pt*16 + m] = __float2bfloat16(pv);
        }
      }
      #pragma unroll
      for (int r = 0; r < 4; ++r){
        #pragma unroll
        for (int o = 1; o < 16; o <<= 1){
          za[r] += __shfl_xor(za[r], o, 64);
          zb[r] += __shfl_xor(zb[r], o, 64);
        }
      }
      if (m == 0){
        #pragma unroll
        for (int r = 0; r < 4; ++r){
          atomicAdd(&zacc[b*NHID + d0      + q4*4 + r], za[r]);
          atomicAdd(&zacc[b*NHID + d0 + 16 + q4*4 + r], zb[r]);
        }
      }
    } else {
      const int v0 = row0 - 256;
      #pragma unroll
      for (int pt = 0; pt < 4; ++pt)
        #pragma unroll
        for (int r = 0; r < 4; ++r){
          Vb[v0      + q4*4 + r][pt*16 + m] = __float2bfloat16(acc[ra][pt][r]*sv[pt]);
          Vb[v0 + 16 + q4*4 + r][pt*16 + m] = __float2bfloat16(acc[rb][pt][r]*sv[pt]);
        }
    }
  }
  __syncthreads();
  // ctx MFMA: wave wv = head wv; 64 toks in 2 K-steps
  floatx4 cx[2][2] = {};
  #pragma unroll
  for (int k0t = 0; k0t < 64; k0t += 32){
    bf16x8 af2[2], bf2[2];
    #pragma unroll
    for (int dt = 0; dt < 2; ++dt) af2[dt] = *(const bf16x8*)&Pb[wv*32 + dt*16 + m][k0t + q4*8];
    #pragma unroll
    for (int et = 0; et < 2; ++et) bf2[et] = *(const bf16x8*)&Vb[wv*32 + et*16 + m][k0t + q4*8];
    #pragma unroll
    for (int dt = 0; dt < 2; ++dt)
      #pragma unroll
      for (int et = 0; et < 2; ++et)
        cx[dt][et] = __builtin_amdgcn_mfma_f32_16x16x32_bf16(af2[dt], bf2[et], cx[dt][et], 0, 0, 0);
  }
  float* cb2 = ctxu + (size_t)(b*NH + wv)*ND*ND;
  #pragma unroll
  for (int dt = 0; dt < 2; ++dt)
    #pragma unroll
    for (int et = 0; et < 2; ++et)
      #pragma unroll
      for (int r = 0; r < 4; ++r)
        atomicAdd(&cb2[(dt*16 + q4*4 + r)*ND + et*16 + m], cx[dt][et][r]);
}

// ---------------- k4 v2: 64 blocks, LDS-staged, coalesced (unchanged).
__launch_bounds__(256)
__global__ void k4_weff(const float* __restrict__ ctxu, const float* __restrict__ zacc,
                        const float* __restrict__ memkv, const float* __restrict__ wout,
                        bf16* __restrict__ wpack){
  __shared__ float ctxL[4][32][32];        // 16384 B
  __shared__ float woutL[64][129];         // 33024 B
  const int t = threadIdx.x;
  const int o0 = blockIdx.x * 64, b = blockIdx.y;
  {
    const float* ws = wout + (size_t)o0*NHID;
    #pragma unroll
    for (int i = 0; i < 32; ++i){
      const int idx = i*256 + t;
      woutL[idx >> 7][idx & 127] = ws[idx];
    }
  }
  if (t < 128){
    const int h = t >> 5;
    const float* mk = memkv + t*NMEM;
    float me[4]; float z = zacc[b*NHID + t];
    #pragma unroll
    for (int j = 0; j < 4; ++j){ me[j] = __expf(mk[j]); z += me[j]; }
    const float invz = 1.0f / z;
    const float* cp = ctxu + (size_t)(b*NH*ND + t)*ND;
    const float* mv = memkv + (size_t)(NHID + h*ND)*NMEM;
    #pragma unroll
    for (int e = 0; e < ND; ++e){
      float ce = cp[e];
      #pragma unroll
      for (int j = 0; j < 4; ++j) ce += me[j]*mv[e*NMEM + j];
      ctxL[h][t & 31][e] = ce * invz;
    }
  }
  __syncthreads();
  const int ol = t & 63, g = t >> 6;
  float out[32] = {};
  #pragma unroll
  for (int e = 0; e < 32; ++e){
    const float we = woutL[ol][g*32 + e];
    #pragma unroll
    for (int d = 0; d < 32; ++d) out[d] += ctxL[g][d][e] * we;
  }
  const int o = o0 + ol, tile = o >> 4, m16 = o & 15;
  #pragma unroll
  for (int q4k = 0; q4k < 4; ++q4k){
    alignas(16) bf16 tmp[8];
    #pragma unroll
    for (int j = 0; j < 8; ++j) tmp[j] = __float2bfloat16(out[q4k*8 + j]);
    *(uint4*)(wpack + ((size_t)((b*4 + g)*16 + tile)*64 + q4k*16 + m16)*8) = *(const uint4*)tmp;
  }
}

// ---------------- K5 v5: fully register-direct (both LDS trips were lane-identity).
// No staging LDS, no hot-loop barriers: 32 operand loads up front, 64 MFMAs,
// then the cross-wave RMSNorm reduction (tiny dedicated LDS).
__launch_bounds__(256)
__global__ void k5_out(float* dout, const bf16* __restrict__ wpack,
                       const float* __restrict__ bout, const float* __restrict__ gout){
  __shared__ float red[256];
  __shared__ float nf[64];
  const int t = threadIdx.x;
  const int pb = blockIdx.x * 64, b = blockIdx.y;
  const int wv = t >> 6, lane = t & 63, m = lane & 15, q4 = lane >> 4;
  bf16x8 wf[4][4], qf[4][4];
  #pragma unroll
  for (int s = 0; s < 4; ++s){
    #pragma unroll
    for (int rt = 0; rt < 4; ++rt)
      wf[s][rt] = *(const bf16x8*)(wpack + ((size_t)((b*4 + s)*16 + wv*4 + rt)*64 + lane)*8);
    #pragma unroll
    for (int pt = 0; pt < 4; ++pt)
      qf[s][pt] = *(const bf16x8*)((const char*)(dout + (size_t)(b*NC + (s*4 + pt)*4 + q4)*NPIX + pb) + m*16);
  }
  floatx4 acc[4][4] = {};
  #pragma unroll
  for (int s = 0; s < 4; ++s)
    #pragma unroll
    for (int rt = 0; rt < 4; ++rt)
      #pragma unroll
      for (int pt = 0; pt < 4; ++pt)
        acc[rt][pt] = __builtin_amdgcn_mfma_f32_16x16x32_bf16(wf[s][rt], qf[s][pt], acc[rt][pt], 0, 0, 0);
  // bias + ssq partials
  float ps[4] = {0.f, 0.f, 0.f, 0.f};
  #pragma unroll
  for (int rt = 0; rt < 4; ++rt){
    const int row = wv*64 + rt*16 + q4*4;
    #pragma unroll
    for (int r = 0; r < 4; ++r){
      const float bias = bout[row + r];
      #pragma unroll
      for (int pt = 0; pt < 4; ++pt){
        acc[rt][pt][r] += bias;
        ps[pt] += acc[rt][pt][r]*acc[rt][pt][r];
      }
    }
  }
  #pragma unroll
  for (int pt = 0; pt < 4; ++pt){
    ps[pt] += __shfl_xor(ps[pt], 16, 64);
    ps[pt] += __shfl_xor(ps[pt], 32, 64);
  }
  if (q4 == 0){
    #pragma unroll
    for (int pt = 0; pt < 4; ++pt) red[wv*64 + pt*16 + m] = ps[pt];
  }
  __syncthreads();
  if (t < 64){
    float tot = red[t] + red[64 + t] + red[128 + t] + red[192 + t];
    nf[t] = 16.0f / fmaxf(sqrtf(tot), 1e-12f);
  }
  __syncthreads();
  float nv[4];
  #pragma unroll
  for (int pt = 0; pt < 4; ++pt) nv[pt] = nf[pt*16 + m];
  #pragma unroll
  for (int rt = 0; rt < 4; ++rt){
    const int row = wv*64 + rt*16 + q4*4;
    #pragma unroll
    for (int r = 0; r < 4; ++r){
      const float gg = gout[row + r];
      float* op = dout + (size_t)(b*NC + row + r)*NPIX + pb + m;
      #pragma unroll
      for (int pt = 0; pt < 4; ++pt)
        op[pt*16] = acc[rt][pt][r]*nv[pt]*gg;
    }
  }
}

extern "C" void kernel_launch(void* const* d_in, const int* in_sizes, int n_in,
                              void* d_out, int out_size, void* d_ws, size_t ws_size,
                              hipStream_t stream) {
  (void)in_sizes; (void)n_in; (void)out_size; (void)ws_size;
  const float* x     = (const float*)d_in[0];
  const float* ng    = (const float*)d_in[1];
  const float* wqkv  = (const float*)d_in[2];
  const float* memkv = (const float*)d_in[3];
  const float* wout  = (const float*)d_in[4];
  const float* bout  = (const float*)d_in[5];
  const float* gout  = (const float*)d_in[6];
  float* dout = (float*)d_out;
  char* ws = (char*)d_ws;
  // workspace layout — total 1,515,520 B (~1.45 MB)
  bf16*  wgpack = (bf16*)(ws);              // 8*24*64*8*2  = 196608
  bf16*  wpack  = (bf16*)(ws + 196608);     // 16*4*16*64*8*2 = 1048576
  float* ctxu   = (float*)(ws + 1245184);   // 16*4*32*32*4 = 262144
  float* zacc   = (float*)(ws + 1507328);   // 16*128*4     = 8192

  kW     <<<dim3(48),      256, 0, stream>>>(wqkv, ng, wgpack, ctxu);  // also zeroes ctxu+zacc
  kA     <<<dim3(64, 16),  256, 0, stream>>>(x, wgpack, dout, ctxu, zacc);
  k4_weff<<<dim3(4, 16),   256, 0, stream>>>(ctxu, zacc, memkv, wout, wpack);
  k5_out <<<dim3(64, 16),  256, 0, stream>>>(dout, wpack, bout, gout);
}